// Round 1
// baseline (278.673 us; speedup 1.0000x reference)
//
#include <hip/hip_runtime.h>

// Problem constants: x (B=64, C=256, T=2048) fp32; conv_weight (256,256,3);
// beta (1,); b (256,). Output spikes (B,C,T) fp32 in {0,1}.
#define C_DIM 256
#define T_DIM 2048
#define NROWS (64 * C_DIM)   // 16384 independent (b,c) recurrences
#define NV 16                // float4 per chunk = 64 floats
#define NCHUNK (T_DIM / (NV * 4))  // 32 chunks

__device__ __forceinline__ float sqrn(float v) { return __fmul_rn(v, v); }

// norm[c] = sum of squares of 768 contiguous floats, in numpy's exact
// pairwise order: 768 -> 384+384 -> 192+192 each -> 96+96 each; each
// 96-block via the 8-accumulator unrolled loop; combine tree
// ((r0+r1)+(r2+r3)) + ((r4+r5)+(r6+r7)). All ops round-to-nearest fp32,
// no FMA contraction (intrinsics).
__global__ __launch_bounds__(64) void norm_kernel(const float* __restrict__ w,
                                                  const float* __restrict__ b,
                                                  float* __restrict__ bn,
                                                  float* __restrict__ ninv) {
    const int c = blockIdx.x;
    const int k = threadIdx.x;
    __shared__ float q[8];
    if (k < 8) {
        const float* a = w + c * 768 + k * 96;
        float r0 = sqrn(a[0]), r1 = sqrn(a[1]), r2 = sqrn(a[2]), r3 = sqrn(a[3]);
        float r4 = sqrn(a[4]), r5 = sqrn(a[5]), r6 = sqrn(a[6]), r7 = sqrn(a[7]);
        #pragma unroll
        for (int i = 8; i < 96; i += 8) {
            r0 = __fadd_rn(r0, sqrn(a[i + 0]));
            r1 = __fadd_rn(r1, sqrn(a[i + 1]));
            r2 = __fadd_rn(r2, sqrn(a[i + 2]));
            r3 = __fadd_rn(r3, sqrn(a[i + 3]));
            r4 = __fadd_rn(r4, sqrn(a[i + 4]));
            r5 = __fadd_rn(r5, sqrn(a[i + 5]));
            r6 = __fadd_rn(r6, sqrn(a[i + 6]));
            r7 = __fadd_rn(r7, sqrn(a[i + 7]));
        }
        q[k] = __fadd_rn(__fadd_rn(__fadd_rn(r0, r1), __fadd_rn(r2, r3)),
                         __fadd_rn(__fadd_rn(r4, r5), __fadd_rn(r6, r7)));
    }
    __syncthreads();
    if (k == 0) {
        // pairwise combine of the eight 96-blocks: matches the
        // 768->384->192->96 recursion tree exactly.
        float s = __fadd_rn(__fadd_rn(__fadd_rn(q[0], q[1]), __fadd_rn(q[2], q[3])),
                            __fadd_rn(__fadd_rn(q[4], q[5]), __fadd_rn(q[6], q[7])));
        bn[c]   = __fmul_rn(b[c], s);                 // b * norm (reset magnitude)
        ninv[c] = 1.0f / __fadd_rn(s, 1e-8f);         // IEEE-correct fp32 div
    }
}

// One LIF recurrence step, numpy fp32 semantics (each op separately rounded):
//   rst  = spk * (b*norm)
//   mem  = (mem - rst)*beta + x*(1-beta)
//   mthr = mem*inv_norm - b
//   spk  = mthr > 0 ? 1 : 0
__device__ __forceinline__ float lif_step(float xv, float& mem, float& spk,
                                          float bnc, float beta, float omb,
                                          float nic, float bc) {
    float rst  = __fmul_rn(spk, bnc);   // spk in {0,1} -> exact 0 or bnc
    mem        = __fadd_rn(__fmul_rn(__fsub_rn(mem, rst), beta),
                           __fmul_rn(xv, omb));
    float mthr = __fsub_rn(__fmul_rn(mem, nic), bc);
    spk        = (mthr > 0.0f) ? 1.0f : 0.0f;
    return spk;
}

// One thread per (b,c) row; register double-buffer of 16 float4 keeps 16
// global_load_dwordx4 in flight per wave to hide HBM latency at 1 wave/CU.
__global__ __launch_bounds__(64, 1) void lif_kernel(const float* __restrict__ x,
                                                    const float* __restrict__ beta_p,
                                                    const float* __restrict__ b,
                                                    const float* __restrict__ bn,
                                                    const float* __restrict__ ninv,
                                                    float* __restrict__ out) {
    const int row = blockIdx.x * 64 + threadIdx.x;   // 0..16383
    const int c   = row & (C_DIM - 1);

    const float beta = beta_p[0];
    const float omb  = __fsub_rn(1.0f, beta);        // 1.0 - beta, rn
    const float bnc  = bn[c];
    const float nic  = ninv[c];
    const float bc   = b[c];

    const float4* xp = (const float4*)(x + (size_t)row * T_DIM);
    float4*       op = (float4*)(out + (size_t)row * T_DIM);

    float4 bufA[NV], bufB[NV];
    #pragma unroll
    for (int i = 0; i < NV; ++i) bufA[i] = xp[i];    // preload chunk 0

    float mem = 0.0f, spk = 0.0f;

    #pragma unroll 1
    for (int ch = 0; ch < NCHUNK; ch += 2) {
        // prefetch chunk ch+1 (always exists: NCHUNK even, ch+1 <= 31)
        #pragma unroll
        for (int i = 0; i < NV; ++i) bufB[i] = xp[(ch + 1) * NV + i];
        // process chunk ch from bufA
        #pragma unroll
        for (int i = 0; i < NV; ++i) {
            float4 v = bufA[i], o;
            o.x = lif_step(v.x, mem, spk, bnc, beta, omb, nic, bc);
            o.y = lif_step(v.y, mem, spk, bnc, beta, omb, nic, bc);
            o.z = lif_step(v.z, mem, spk, bnc, beta, omb, nic, bc);
            o.w = lif_step(v.w, mem, spk, bnc, beta, omb, nic, bc);
            op[ch * NV + i] = o;
        }
        // prefetch chunk ch+2
        if (ch + 2 < NCHUNK) {
            #pragma unroll
            for (int i = 0; i < NV; ++i) bufA[i] = xp[(ch + 2) * NV + i];
        }
        // process chunk ch+1 from bufB
        #pragma unroll
        for (int i = 0; i < NV; ++i) {
            float4 v = bufB[i], o;
            o.x = lif_step(v.x, mem, spk, bnc, beta, omb, nic, bc);
            o.y = lif_step(v.y, mem, spk, bnc, beta, omb, nic, bc);
            o.z = lif_step(v.z, mem, spk, bnc, beta, omb, nic, bc);
            o.w = lif_step(v.w, mem, spk, bnc, beta, omb, nic, bc);
            op[(ch + 1) * NV + i] = o;
        }
    }
}

extern "C" void kernel_launch(void* const* d_in, const int* in_sizes, int n_in,
                              void* d_out, int out_size, void* d_ws, size_t ws_size,
                              hipStream_t stream) {
    const float* x    = (const float*)d_in[0];
    const float* w    = (const float*)d_in[1];
    const float* beta = (const float*)d_in[2];
    const float* b    = (const float*)d_in[3];
    float* out  = (float*)d_out;
    float* bn   = (float*)d_ws;          // 256 floats
    float* ninv = bn + C_DIM;            // 256 floats

    norm_kernel<<<C_DIM, 64, 0, stream>>>(w, b, bn, ninv);
    lif_kernel<<<NROWS / 64, 64, 0, stream>>>(x, beta, b, bn, ninv, out);
}